// Round 1
// baseline (849.117 us; speedup 1.0000x reference)
//
#include <hip/hip_runtime.h>
#include <stdint.h>

// Problem dims
static constexpr int cN1 = 128;   // src tokens
static constexpr int cE  = 256;   // embedding
static constexpr int cH  = 512;   // hidden
static constexpr int cV  = 32000; // vocab
static constexpr int cG  = 4 * cH; // 2048 gate rows

// ---------------- ws layout (bytes) ----------------
static constexpr size_t O_CTR = 0;                             // int[256] barrier counters
static constexpr size_t O_ACC = 1024;                          // float[2]: kl, terms
static constexpr size_t O_WPK = 4096;                          // bf16 [2][2048][512] packed
static constexpr size_t O_XG  = O_WPK + 2ull * cG * cH * 2;    // f32 [2][128][2048]
static constexpr size_t O_HF  = O_XG  + 2ull * cN1 * cG * 4;   // f32 [129][512]
static constexpr size_t O_HB  = O_HF  + 129ull * cH * 4;       // f32 [129][512]
static constexpr size_t O_U   = O_HB  + 129ull * cH * 4;       // f32 [128][512]
static constexpr size_t O_S   = O_U   + (size_t)cN1 * cH * 4;
static constexpr size_t O_Z1  = O_S   + (size_t)cN1 * cH * 4;
static constexpr size_t O_Z2  = O_Z1  + (size_t)cN1 * cH * 4;
static constexpr size_t O_PM  = O_Z2  + (size_t)cN1 * cH * 4;  // float2 [2][250][128]
static constexpr size_t O_G1  = O_PM  + 2ull * 250 * 128 * 8;  // f32 [128]
static constexpr size_t O_G2  = O_G1  + 128 * 4;               // f32 [128][16]

// ---------------- helpers ----------------
__device__ inline uint32_t f2bf(float f) {
  uint32_t x = __float_as_uint(f);
  return (x + 0x7FFFu + ((x >> 16) & 1u)) >> 16; // RNE bf16
}
__device__ inline void mac2(float& s, uint32_t w, float h0, float h1) {
  s += __uint_as_float(w << 16) * h0;
  s += __uint_as_float(w & 0xffff0000u) * h1;
}
__device__ inline uint64_t splitmix64(uint64_t x) {
  x += 0x9E3779B97F4A7C15ull;
  x = (x ^ (x >> 30)) * 0xBF58476D1CE4E5B9ull;
  x = (x ^ (x >> 27)) * 0x94D049BB133111EBull;
  return x ^ (x >> 31);
}
__device__ inline float rng_normal(uint32_t idx, uint32_t stream_id) {
  uint64_t h = splitmix64(((uint64_t)stream_id << 32) | (uint64_t)idx);
  uint32_t a = (uint32_t)(h >> 32), b = (uint32_t)h;
  float u1 = (float)((a >> 8) + 1u) * (1.0f / 16777217.0f); // (0,1]
  float u2 = (float)(b >> 8) * (1.0f / 16777216.0f);
  float r = sqrtf(-2.0f * logf(u1));
  return r * __cosf(6.28318530717958647692f * u2);
}

// ---------------- K0: pack Whh (both dirs) into per-block bf16 layout ----------------
// layout: [dir][bi(16)][rg(16)][r(8)][kc(32)][16 bf16]; local row lr=rg*8+r maps to
// global gate row G = (lr>>5)*512 + bi*32 + (lr&31)  (gate-major i,f,g,o within block slice)
__global__ __launch_bounds__(256) void k_pack(const float* __restrict__ Whh_f,
                                              const float* __restrict__ Whh_b,
                                              uint16_t* __restrict__ wpk) {
  int d = blockIdx.x * 256 + threadIdx.x; // 0..262143, 8 bf16 each
  int half = d & 1;
  int kc   = (d >> 1) & 31;
  int r    = (d >> 6) & 7;
  int rg   = (d >> 9) & 15;
  int bi   = (d >> 13) & 15;
  int dir  = (d >> 17) & 1;
  int lr = rg * 8 + r;
  int G  = (lr >> 5) * cH + bi * 32 + (lr & 31);
  int k0 = kc * 16 + half * 8;
  const float* src = (dir ? Whh_b : Whh_f) + (size_t)G * cH + k0;
  float4 v0 = *(const float4*)(src);
  float4 v1 = *(const float4*)(src + 4);
  uint4 p;
  p.x = f2bf(v0.x) | (f2bf(v0.y) << 16);
  p.y = f2bf(v0.z) | (f2bf(v0.w) << 16);
  p.z = f2bf(v1.x) | (f2bf(v1.y) << 16);
  p.w = f2bf(v1.z) | (f2bf(v1.w) << 16);
  ((uint4*)wpk)[d] = p;
}

// ---------------- K1: embedding gather + xg = x@Wih^T + bih + bhh (both dirs) ----------------
// grid (8 tokchunk, 16 rowchunk, 2 dir), block 256
__global__ __launch_bounds__(256) void k_embxg(const int* __restrict__ words,
                                               const float* __restrict__ emb,
                                               const float* __restrict__ Wih_f,
                                               const float* __restrict__ bih_f,
                                               const float* __restrict__ bhh_f,
                                               const float* __restrict__ Wih_b,
                                               const float* __restrict__ bih_b,
                                               const float* __restrict__ bhh_b,
                                               float* __restrict__ xg) {
  int tc = blockIdx.x, rc = blockIdx.y, dir = blockIdx.z;
  const float* Wih = dir ? Wih_b : Wih_f;
  const float* bi_ = dir ? bih_b : bih_f;
  const float* bh_ = dir ? bhh_b : bhh_f;
  __shared__ float xs[16][cE];
  __shared__ float bs[128][20];
  int tid = threadIdx.x;
  { // stage x tile (with gather); dir=1 reads reversed tokens
    int i = tid >> 4, part = tid & 15;
    int tg = tc * 16 + i;
    int tok = dir ? (127 - tg) : tg;
    int w = words[tok];
    const float4* src = (const float4*)(emb + (size_t)w * cE + part * 16);
    float4* dst = (float4*)(&xs[i][part * 16]);
    dst[0] = src[0]; dst[1] = src[1]; dst[2] = src[2]; dst[3] = src[3];
  }
  float acc[2][4] = {};
  int tx = tid & 31;  // rows tx*4..+4 (of 128)
  int ty = tid >> 5;  // tokens ty*2, ty*2+1 handled... actually ty in [0,8): toks ty*2+i
  for (int kc = 0; kc < 16; kc++) {
    __syncthreads();
    { // stage W tile [128 rows][16 k]
      int r = tid >> 1, half = tid & 1;
      const float4* src = (const float4*)(Wih + (size_t)(rc * 128 + r) * cE + kc * 16 + half * 8);
      float4* dst = (float4*)(&bs[r][half * 8]);
      dst[0] = src[0]; dst[1] = src[1];
    }
    __syncthreads();
#pragma unroll
    for (int k4 = 0; k4 < 4; k4++) {
      float4 a0 = *(const float4*)(&xs[ty * 2 + 0][kc * 16 + k4 * 4]);
      float4 a1 = *(const float4*)(&xs[ty * 2 + 1][kc * 16 + k4 * 4]);
#pragma unroll
      for (int j = 0; j < 4; j++) {
        float4 b = *(const float4*)(&bs[tx * 4 + j][k4 * 4]);
        acc[0][j] += a0.x * b.x + a0.y * b.y + a0.z * b.z + a0.w * b.w;
        acc[1][j] += a1.x * b.x + a1.y * b.y + a1.z * b.z + a1.w * b.w;
      }
    }
  }
#pragma unroll
  for (int i = 0; i < 2; i++) {
    int tg = tc * 16 + ty * 2 + i;
#pragma unroll
    for (int j = 0; j < 4; j++) {
      int r = rc * 128 + tx * 4 + j;
      xg[((size_t)dir * cN1 + tg) * cG + r] = acc[i][j] + bi_[r] + bh_[r];
    }
  }
}

// ---------------- K2: LSTM scan, 16 blocks/dir, custom inter-block barrier per step ----------------
__global__ __launch_bounds__(512, 1) void k_lstm(const uint16_t* __restrict__ wpk,
                                                 const float* __restrict__ xg,
                                                 float* __restrict__ hbuf_f,
                                                 float* __restrict__ hbuf_b,
                                                 int* __restrict__ ctr) {
  int blk = blockIdx.x;
  int dir = blk >> 4;
  int bi  = blk & 15;
  const float* xgd = xg + (size_t)dir * cN1 * cG;
  float* hbuf = dir ? hbuf_b : hbuf_f;
  int* myctr = ctr + dir * 128;
  int tid = threadIdx.x;
  int kc = tid & 31;   // k chunk: k in [kc*16, +16)
  int rg = tid >> 5;   // row group: local rows [rg*8, +8)
  __shared__ float h_lds[512];
  __shared__ float psum[128 * 36];
  __shared__ float gate_lds[128];
  __shared__ float c_lds[32];
  if (tid < 32) c_lds[tid] = 0.0f;
  const uint16_t* wbase = wpk + (size_t)(dir * 16 + bi) * 65536;

  for (int t = 0; t < 128; t++) {
    // stage h_{t} (h before consuming token t)
    if (t == 0) h_lds[tid] = 0.0f;
    else h_lds[tid] = __hip_atomic_load(&hbuf[(size_t)t * 512 + tid],
                                        __ATOMIC_RELAXED, __HIP_MEMORY_SCOPE_AGENT);
    __syncthreads();
    float hr[16];
#pragma unroll
    for (int q = 0; q < 4; q++) {
      float4 v = *(const float4*)(&h_lds[kc * 16 + q * 4]);
      hr[q * 4 + 0] = v.x; hr[q * 4 + 1] = v.y; hr[q * 4 + 2] = v.z; hr[q * 4 + 3] = v.w;
    }
#pragma unroll
    for (int r = 0; r < 8; r++) {
      const uint16_t* wp = wbase + ((size_t)(rg * 8 + r) * 32 + kc) * 16;
      uint4 w0 = *(const uint4*)(wp);
      uint4 w1 = *(const uint4*)(wp + 8);
      float s = 0.f;
      mac2(s, w0.x, hr[0], hr[1]);  mac2(s, w0.y, hr[2], hr[3]);
      mac2(s, w0.z, hr[4], hr[5]);  mac2(s, w0.w, hr[6], hr[7]);
      mac2(s, w1.x, hr[8], hr[9]);  mac2(s, w1.y, hr[10], hr[11]);
      mac2(s, w1.z, hr[12], hr[13]); mac2(s, w1.w, hr[14], hr[15]);
      psum[(rg * 8 + r) * 36 + kc] = s;
    }
    __syncthreads();
    if (tid < 128) {
      int lr = tid;
      float ssum = 0.f;
#pragma unroll
      for (int q = 0; q < 8; q++) {
        float4 v = *(const float4*)(&psum[lr * 36 + q * 4]);
        ssum += v.x + v.y + v.z + v.w;
      }
      int G = (lr >> 5) * cH + bi * 32 + (lr & 31);
      gate_lds[lr] = ssum + xgd[(size_t)t * cG + G];
    }
    __syncthreads();
    if (tid < 32) {
      float gi = gate_lds[tid];
      float gf = gate_lds[32 + tid];
      float gg = gate_lds[64 + tid];
      float go = gate_lds[96 + tid];
      float c = c_lds[tid];
      float si = 1.f / (1.f + __expf(-gi));
      float sf = 1.f / (1.f + __expf(-gf));
      float so = 1.f / (1.f + __expf(-go));
      c = sf * c + si * tanhf(gg);
      float h = so * tanhf(c);
      c_lds[tid] = c;
      __hip_atomic_store(&hbuf[(size_t)(t + 1) * 512 + bi * 32 + tid], h,
                         __ATOMIC_RELEASE, __HIP_MEMORY_SCOPE_AGENT);
    }
    __syncthreads();
    if (tid == 0) {
      __hip_atomic_fetch_add(&myctr[t], 1, __ATOMIC_ACQ_REL, __HIP_MEMORY_SCOPE_AGENT);
      int it = 0; // bounded spin: fail fast instead of hanging
      while (__hip_atomic_load(&myctr[t], __ATOMIC_ACQUIRE, __HIP_MEMORY_SCOPE_AGENT) < 16 &&
             it < (1 << 18)) it++;
    }
    __syncthreads();
  }
}

// ---------------- K3: u = h@UW^T + Ub ; s = softplus(h@SW^T + Sb) ----------------
// grid (8 tokchunk, 32 rowchunk), block 256; virtual rows 0..1023 = [UW;SW]
__global__ __launch_bounds__(256) void k_us(const float* __restrict__ hbuf_f,
                                            const float* __restrict__ hbuf_b,
                                            const float* __restrict__ UW,
                                            const float* __restrict__ Ub,
                                            const float* __restrict__ SW,
                                            const float* __restrict__ Sb,
                                            float* __restrict__ u,
                                            float* __restrict__ s) {
  int tcb = blockIdx.x, rcb = blockIdx.y;
  __shared__ float hs[16][1024];
  int tid = threadIdx.x;
  for (int q = tid; q < 16 * 256; q += 256) {
    int i = q >> 8, qq = q & 255;
    int k = qq * 4;
    int T = tcb * 16 + i;
    float4 v;
    if (k < 512) v = *(const float4*)(&hbuf_f[(size_t)(T + 1) * 512 + k]);
    else         v = *(const float4*)(&hbuf_b[(size_t)(128 - T) * 512 + (k - 512)]);
    *(float4*)(&hs[i][k]) = v;
  }
  __syncthreads();
  int rl = tid & 31, tp = tid >> 5;
  int rv = rcb * 32 + rl;
  const float* wrow = (rv < 512) ? (UW + (size_t)rv * 1024) : (SW + (size_t)(rv - 512) * 1024);
  float acc0 = 0.f, acc1 = 0.f;
  for (int k = 0; k < 1024; k += 4) {
    float4 w = *(const float4*)(wrow + k);
    float4 a = *(const float4*)(&hs[tp][k]);
    float4 b = *(const float4*)(&hs[tp + 8][k]);
    acc0 += w.x * a.x + w.y * a.y + w.z * a.z + w.w * a.w;
    acc1 += w.x * b.x + w.y * b.y + w.z * b.z + w.w * b.w;
  }
  int T0 = tcb * 16 + tp, T1 = T0 + 8;
  if (rv < 512) {
    float b = Ub[rv];
    u[(size_t)T0 * 512 + rv] = acc0 + b;
    u[(size_t)T1 * 512 + rv] = acc1 + b;
  } else {
    float b = Sb[rv - 512];
    float x0 = acc0 + b, x1 = acc1 + b;
    s[(size_t)T0 * 512 + rv - 512] = (x0 > 20.f) ? x0 : log1pf(__expf(x0));
    s[(size_t)T1 * 512 + rv - 512] = (x1 > 20.f) ? x1 : log1pf(__expf(x1));
  }
}

// ---------------- K3b: sample z1,z2 and accumulate KL ----------------
__global__ __launch_bounds__(256) void k_sample(const float* __restrict__ u,
                                                const float* __restrict__ s,
                                                float* __restrict__ z1,
                                                float* __restrict__ z2,
                                                float* __restrict__ acc_kl) {
  int idx = blockIdx.x * 256 + threadIdx.x; // 65536 total
  float uu = u[idx], ss = s[idx];
  z1[idx] = uu + ss * rng_normal((uint32_t)idx, 1u);
  z2[idx] = uu + ss * rng_normal((uint32_t)idx, 2u);
  float kle = 0.5f * (ss * ss + uu * uu - 1.0f - 2.0f * logf(fmaxf(ss, 1e-37f)));
  __shared__ float red[256];
  red[threadIdx.x] = kle;
  __syncthreads();
  for (int off = 128; off; off >>= 1) {
    if (threadIdx.x < off) red[threadIdx.x] += red[threadIdx.x + off];
    __syncthreads();
  }
  if (threadIdx.x == 0) atomicAdd(acc_kl, red[0]);
}

// ---------------- K4: fused logits GEMM + online per-row (max,sumexp) partials + gathers ----------------
// grid (250 word-chunks, 2 matrices), block 256; tile 128 rows x 128 words, k=512
__global__ __launch_bounds__(256) void k_logits(const float* __restrict__ z1,
                                                const float* __restrict__ z2,
                                                const float* __restrict__ fW,
                                                const float* __restrict__ fb,
                                                const float* __restrict__ gW,
                                                const float* __restrict__ gb,
                                                const int* __restrict__ words_l1,
                                                const int* __restrict__ words_l2,
                                                float* __restrict__ pm,
                                                float* __restrict__ g1,
                                                float* __restrict__ g2) {
  int gx = blockIdx.x, mat = blockIdx.y;
  const float* Z = mat ? z2 : z1;
  const float* W = mat ? gW : fW;
  const float* B = mat ? gb : fb;
  int w0 = gx * 128;
  __shared__ float As[128][20];
  __shared__ float Bs[128][20];
  __shared__ float2 red[128][16];
  __shared__ int wl1[128];
  __shared__ int wl2s[16];
  int tid = threadIdx.x;
  if (tid < 128) wl1[tid] = words_l1[tid];
  if (tid < 16) wl2s[tid] = words_l2[tid];
  float acc[8][8] = {};
  int tx = tid & 15, ty = tid >> 4;
  for (int kc = 0; kc < 32; kc++) {
    __syncthreads();
    {
      int r = tid >> 1, half = tid & 1;
      const float4* sa = (const float4*)(Z + (size_t)r * 512 + kc * 16 + half * 8);
      float4* da = (float4*)(&As[r][half * 8]);
      da[0] = sa[0]; da[1] = sa[1];
      const float4* sb = (const float4*)(W + (size_t)(w0 + r) * 512 + kc * 16 + half * 8);
      float4* db = (float4*)(&Bs[r][half * 8]);
      db[0] = sb[0]; db[1] = sb[1];
    }
    __syncthreads();
#pragma unroll
    for (int k4 = 0; k4 < 4; k4++) {
      float4 a[8], b[8];
#pragma unroll
      for (int i = 0; i < 8; i++) a[i] = *(const float4*)(&As[ty * 8 + i][k4 * 4]);
#pragma unroll
      for (int j = 0; j < 8; j++) b[j] = *(const float4*)(&Bs[tx * 8 + j][k4 * 4]);
#pragma unroll
      for (int i = 0; i < 8; i++)
#pragma unroll
        for (int j = 0; j < 8; j++)
          acc[i][j] += a[i].x * b[j].x + a[i].y * b[j].y + a[i].z * b[j].z + a[i].w * b[j].w;
    }
  }
  float bj[8];
#pragma unroll
  for (int j = 0; j < 8; j++) bj[j] = B[w0 + tx * 8 + j];
  // gathers (unique writer per target word)
  if (mat == 0) {
#pragma unroll
    for (int i = 0; i < 8; i++) {
      int row = ty * 8 + i;
      int d = wl1[row] - (w0 + tx * 8);
      if (d >= 0 && d < 8) {
        float v = 0.f;
#pragma unroll
        for (int j = 0; j < 8; j++) v = (j == d) ? (acc[i][j] + bj[j]) : v;
        g1[row] = v;
      }
    }
  } else {
    for (int l = 0; l < 16; l++) {
      int d = wl2s[l] - (w0 + tx * 8);
      if (d >= 0 && d < 8) {
#pragma unroll
        for (int i = 0; i < 8; i++) {
          float v = 0.f;
#pragma unroll
          for (int j = 0; j < 8; j++) v = (j == d) ? (acc[i][j] + bj[j]) : v;
          g2[(ty * 8 + i) * 16 + l] = v;
        }
      }
    }
  }
  // per-thread (max, sumexp) over its 8 words, per row
#pragma unroll
  for (int i = 0; i < 8; i++) {
    float m = -1e30f;
#pragma unroll
    for (int j = 0; j < 8; j++) m = fmaxf(m, acc[i][j] + bj[j]);
    float se = 0.f;
#pragma unroll
    for (int j = 0; j < 8; j++) se += __expf(acc[i][j] + bj[j] - m);
    red[ty * 8 + i][tx] = make_float2(m, se);
  }
  __syncthreads();
  if (tid < 128) {
    float m = -1e30f, se = 0.f;
    for (int x = 0; x < 16; x++) {
      float2 p = red[tid][x];
      if (p.x > m) { se = se * __expf(m - p.x) + p.y; m = p.x; }
      else se += p.y * __expf(p.x - m);
    }
    float2* dst = (float2*)pm + ((size_t)mat * 250 + gx) * 128 + tid;
    *dst = make_float2(m, se);
  }
}

// ---------------- K5: combine per-chunk (m,s) -> lse; accumulate terms ----------------
__global__ __launch_bounds__(256) void k_combine(const float* __restrict__ pm,
                                                 const float* __restrict__ g1,
                                                 const float* __restrict__ g2,
                                                 float* __restrict__ acc_terms) {
  int row = blockIdx.x, mat = blockIdx.y;
  int tid = threadIdx.x;
  const float2* p = (const float2*)pm + (size_t)mat * 250 * 128 + row;
  float m = -1e30f, se = 0.f;
  if (tid < 250) { float2 v = p[(size_t)tid * 128]; m = v.x; se = v.y; }
  __shared__ float2 red[256];
  red[tid] = make_float2(m, se);
  __syncthreads();
  for (int off = 128; off; off >>= 1) {
    if (tid < off) {
      float2 a = red[tid], b = red[tid + off];
      if (b.x > a.x) { a.y = a.y * __expf(a.x - b.x) + b.y; a.x = b.x; }
      else a.y += b.y * __expf(b.x - a.x);
      red[tid] = a;
    }
    __syncthreads();
  }
  if (tid == 0) {
    float lse = red[0].x + logf(red[0].y);
    float v;
    if (mat == 0) v = g1[row] - lse;
    else {
      float sg = 0.f;
      for (int l = 0; l < 16; l++) sg += g2[row * 16 + l];
      v = sg * (1.0f / 16.0f) - lse;
    }
    atomicAdd(acc_terms, v);
  }
}

// ---------------- K6: final scalar ----------------
__global__ void k_final(const float* __restrict__ acc, float* __restrict__ out) {
  out[0] = acc[1] - acc[0]; // -kl + term1 + term2
}

extern "C" void kernel_launch(void* const* d_in, const int* in_sizes, int n_in,
                              void* d_out, int out_size, void* d_ws, size_t ws_size,
                              hipStream_t stream) {
  (void)in_sizes; (void)n_in; (void)out_size; (void)ws_size;
  const int*   words_l1 = (const int*)d_in[0];
  const int*   words_l2 = (const int*)d_in[1];
  const float* emb      = (const float*)d_in[2];
  const float* Wih_f    = (const float*)d_in[3];
  const float* Whh_f    = (const float*)d_in[4];
  const float* bih_f    = (const float*)d_in[5];
  const float* bhh_f    = (const float*)d_in[6];
  const float* Wih_b    = (const float*)d_in[7];
  const float* Whh_b    = (const float*)d_in[8];
  const float* bih_b    = (const float*)d_in[9];
  const float* bhh_b    = (const float*)d_in[10];
  const float* UW       = (const float*)d_in[11];
  const float* Ub       = (const float*)d_in[12];
  const float* SW       = (const float*)d_in[13];
  const float* Sb       = (const float*)d_in[14];
  const float* fW       = (const float*)d_in[15];
  const float* fb       = (const float*)d_in[16];
  const float* gW       = (const float*)d_in[17];
  const float* gb       = (const float*)d_in[18];

  char* ws = (char*)d_ws;
  int*      ctr  = (int*)(ws + O_CTR);
  float*    acc  = (float*)(ws + O_ACC);
  uint16_t* wpk  = (uint16_t*)(ws + O_WPK);
  float*    xg   = (float*)(ws + O_XG);
  float*    hf   = (float*)(ws + O_HF);
  float*    hb   = (float*)(ws + O_HB);
  float*    u    = (float*)(ws + O_U);
  float*    s    = (float*)(ws + O_S);
  float*    z1   = (float*)(ws + O_Z1);
  float*    z2   = (float*)(ws + O_Z2);
  float*    pm   = (float*)(ws + O_PM);
  float*    g1   = (float*)(ws + O_G1);
  float*    g2   = (float*)(ws + O_G2);

  hipMemsetAsync(ws, 0, 2048, stream); // counters + accumulators

  k_pack<<<1024, 256, 0, stream>>>(Whh_f, Whh_b, wpk);
  k_embxg<<<dim3(8, 16, 2), 256, 0, stream>>>(words_l1, emb, Wih_f, bih_f, bhh_f,
                                              Wih_b, bih_b, bhh_b, xg);
  k_lstm<<<32, 512, 0, stream>>>(wpk, xg, hf, hb, ctr);
  k_us<<<dim3(8, 32), 256, 0, stream>>>(hf, hb, UW, Ub, SW, Sb, u, s);
  k_sample<<<256, 256, 0, stream>>>(u, s, z1, z2, &acc[0]);
  k_logits<<<dim3(250, 2), 256, 0, stream>>>(z1, z2, fW, fb, gW, gb,
                                             words_l1, words_l2, pm, g1, g2);
  k_combine<<<dim3(128, 2), 256, 0, stream>>>(pm, g1, g2, &acc[1]);
  k_final<<<1, 1, 0, stream>>>(acc, (float*)d_out);
}

// Round 2
// 735.785 us; speedup vs baseline: 1.1540x; 1.1540x over previous
//
#include <hip/hip_runtime.h>
#include <stdint.h>

// Problem dims
static constexpr int cN1 = 128;   // src tokens
static constexpr int cE  = 256;   // embedding
static constexpr int cH  = 512;   // hidden
static constexpr int cV  = 32000; // vocab
static constexpr int cG  = 4 * cH; // 2048 gate rows

// ---------------- ws layout (bytes) ----------------
static constexpr size_t O_DUM = 0;                             // dummy sink (never written)
static constexpr size_t O_ACC = 1024;                          // float[2]: kl, terms
static constexpr size_t O_WPK = 4096;                          // bf16 [2][2048][512] packed
static constexpr size_t O_XG  = O_WPK + 2ull * cG * cH * 2;    // f32 [2][128][2048]
static constexpr size_t O_HF  = O_XG  + 2ull * cN1 * cG * 4;   // (f32,val+tag) [129][512] = 8B each
static constexpr size_t O_HB  = O_HF  + 129ull * cH * 8;
static constexpr size_t O_U   = O_HB  + 129ull * cH * 8;       // f32 [128][512]
static constexpr size_t O_S   = O_U   + (size_t)cN1 * cH * 4;
static constexpr size_t O_Z1  = O_S   + (size_t)cN1 * cH * 4;
static constexpr size_t O_Z2  = O_Z1  + (size_t)cN1 * cH * 4;
static constexpr size_t O_PM  = O_Z2  + (size_t)cN1 * cH * 4;  // float2 [2][250][128]
static constexpr size_t O_G1  = O_PM  + 2ull * 250 * 128 * 8;  // f32 [128]
static constexpr size_t O_G2  = O_G1  + 512;                   // f32 [128][16]

// ---------------- helpers ----------------
__device__ inline uint32_t f2bf(float f) {
  uint32_t x = __float_as_uint(f);
  return (x + 0x7FFFu + ((x >> 16) & 1u)) >> 16; // RNE bf16
}
__device__ inline void mac2(float& s, uint32_t w, float h0, float h1) {
  s += __uint_as_float(w << 16) * h0;
  s += __uint_as_float(w & 0xffff0000u) * h1;
}
__device__ inline uint64_t splitmix64(uint64_t x) {
  x += 0x9E3779B97F4A7C15ull;
  x = (x ^ (x >> 30)) * 0xBF58476D1CE4E5B9ull;
  x = (x ^ (x >> 27)) * 0x94D049BB133111EBull;
  return x ^ (x >> 31);
}
__device__ inline float rng_normal(uint32_t idx, uint32_t stream_id) {
  uint64_t h = splitmix64(((uint64_t)stream_id << 32) | (uint64_t)idx);
  uint32_t a = (uint32_t)(h >> 32), b = (uint32_t)h;
  float u1 = (float)((a >> 8) + 1u) * (1.0f / 16777217.0f); // (0,1]
  float u2 = (float)(b >> 8) * (1.0f / 16777216.0f);
  float r = sqrtf(-2.0f * logf(u1));
  return r * __cosf(6.28318530717958647692f * u2);
}
__device__ inline float fast_sigmoid(float x) { return 1.f / (1.f + __expf(-x)); }
__device__ inline float fast_tanh(float x) {
  float e = __expf(2.f * x);
  return (e - 1.f) / (e + 1.f);
}

// ---------------- K0: pack Whh (both dirs) into per-block bf16 layout ----------------
// wpk per (dir,bi): 128 local rows x 32 kc x 16 bf16. Entry (lr,kc), uint32 m (0..7):
//   lo = W[G][kc+64m], hi = W[G][kc+64m+32];  G = (lr>>5)*512 + bi*32 + (lr&31)
// Consumer lane kc holds h[kc+32q]: mac2 pairs (hr[2m],hr[2m+1]) = (h[kc+64m],h[kc+64m+32]).
__global__ __launch_bounds__(256) void k_pack(const float* __restrict__ Whh_f,
                                              const float* __restrict__ Whh_b,
                                              uint16_t* __restrict__ wpk) {
  int d = blockIdx.x * 256 + threadIdx.x; // 131072 threads: one per (dir,bi,rg,r,kc)
  int kc  = d & 31;
  int r   = (d >> 5) & 7;
  int rg  = (d >> 8) & 15;
  int bi  = (d >> 12) & 15;
  int dir = (d >> 16) & 1;
  int lr = rg * 8 + r;
  int G  = (lr >> 5) * cH + bi * 32 + (lr & 31);
  const float* src = (dir ? Whh_b : Whh_f) + (size_t)G * cH;
  uint32_t m[8];
#pragma unroll
  for (int q = 0; q < 8; q++) {
    float lo = src[kc + 64 * q];
    float hi = src[kc + 64 * q + 32];
    m[q] = f2bf(lo) | (f2bf(hi) << 16);
  }
  uint4* dst = (uint4*)wpk + ((size_t)(dir * 16 + bi) * 8192 + ((size_t)lr * 32 + kc) * 2);
  dst[0] = make_uint4(m[0], m[1], m[2], m[3]);
  dst[1] = make_uint4(m[4], m[5], m[6], m[7]);
}

// ---------------- K1: embedding gather + xg = x@Wih^T + bih + bhh (both dirs) ----------------
__global__ __launch_bounds__(256) void k_embxg(const int* __restrict__ words,
                                               const float* __restrict__ emb,
                                               const float* __restrict__ Wih_f,
                                               const float* __restrict__ bih_f,
                                               const float* __restrict__ bhh_f,
                                               const float* __restrict__ Wih_b,
                                               const float* __restrict__ bih_b,
                                               const float* __restrict__ bhh_b,
                                               float* __restrict__ xg) {
  int tc = blockIdx.x, rc = blockIdx.y, dir = blockIdx.z;
  const float* Wih = dir ? Wih_b : Wih_f;
  const float* bi_ = dir ? bih_b : bih_f;
  const float* bh_ = dir ? bhh_b : bhh_f;
  __shared__ float xs[16][cE];
  __shared__ float bs[128][20];
  int tid = threadIdx.x;
  {
    int i = tid >> 4, part = tid & 15;
    int tg = tc * 16 + i;
    int tok = dir ? (127 - tg) : tg;
    int w = words[tok];
    const float4* src = (const float4*)(emb + (size_t)w * cE + part * 16);
    float4* dst = (float4*)(&xs[i][part * 16]);
    dst[0] = src[0]; dst[1] = src[1]; dst[2] = src[2]; dst[3] = src[3];
  }
  float acc[2][4] = {};
  int tx = tid & 31;
  int ty = tid >> 5;
  for (int kc = 0; kc < 16; kc++) {
    __syncthreads();
    {
      int r = tid >> 1, half = tid & 1;
      const float4* src = (const float4*)(Wih + (size_t)(rc * 128 + r) * cE + kc * 16 + half * 8);
      float4* dst = (float4*)(&bs[r][half * 8]);
      dst[0] = src[0]; dst[1] = src[1];
    }
    __syncthreads();
#pragma unroll
    for (int k4 = 0; k4 < 4; k4++) {
      float4 a0 = *(const float4*)(&xs[ty * 2 + 0][kc * 16 + k4 * 4]);
      float4 a1 = *(const float4*)(&xs[ty * 2 + 1][kc * 16 + k4 * 4]);
#pragma unroll
      for (int j = 0; j < 4; j++) {
        float4 b = *(const float4*)(&bs[tx * 4 + j][k4 * 4]);
        acc[0][j] += a0.x * b.x + a0.y * b.y + a0.z * b.z + a0.w * b.w;
        acc[1][j] += a1.x * b.x + a1.y * b.y + a1.z * b.z + a1.w * b.w;
      }
    }
  }
#pragma unroll
  for (int i = 0; i < 2; i++) {
    int tg = tc * 16 + ty * 2 + i;
#pragma unroll
    for (int j = 0; j < 4; j++) {
      int r = rc * 128 + tx * 4 + j;
      xg[((size_t)dir * cN1 + tg) * cG + r] = acc[i][j] + bi_[r] + bh_[r];
    }
  }
}

// ---------------- K2: LSTM scan — register weights, data-as-flag sync ----------------
// 256 blocks x 512 thr. Active: blockIdx%8==dir(0/1), blockIdx/8<16 → bi. All 256 blocks
// co-resident (1/CU) so correctness never depends on the %8→XCD placement heuristic.
// h element = uint64 {tag=step (hi32), float bits (lo32)}; ws poison 0xAAAAAAAA != any tag.
__global__ __launch_bounds__(512, 1) void k_lstm(const uint16_t* __restrict__ wpk,
                                                 const float* __restrict__ xg,
                                                 uint64_t* __restrict__ hf64,
                                                 uint64_t* __restrict__ hb64,
                                                 const float* __restrict__ fW,
                                                 const float* __restrict__ gW,
                                                 float* __restrict__ dummy) {
  int xcd = blockIdx.x & 7;
  int wk  = blockIdx.x >> 3;
  int tid = threadIdx.x;
  if (xcd >= 2 || wk >= 16) {
    // idle blocks: warm fW/gW into LLC for k_logits
    const size_t half4 = (size_t)cV * cH / 4; // float4 count per matrix
    float s = 0.f;
    for (size_t i = (size_t)blockIdx.x * 512 + tid; i < 2 * half4; i += 256ull * 512) {
      float4 v = (i < half4) ? ((const float4*)fW)[i] : ((const float4*)gW)[i - half4];
      s += v.x + v.y + v.z + v.w;
    }
    if (s == 123456789.0f) dummy[0] = s; // never true; defeats DCE
    return;
  }
  int dir = xcd, bi = wk;
  const float* xgd = xg + (size_t)dir * cN1 * cG + bi * 32;
  uint64_t* hbuf = dir ? hb64 : hf64;
  int kc = tid & 31, rg = tid >> 5;
  __shared__ float h_lds[512];
  __shared__ float gate_lds[128];
  // weights -> registers (64 VGPRs of bf16 pairs)
  uint4 w0[8], w1[8];
  {
    const uint4* wb = (const uint4*)wpk + (size_t)(dir * 16 + bi) * 8192;
#pragma unroll
    for (int r = 0; r < 8; r++) {
      const uint4* ep = wb + ((size_t)(rg * 8 + r) * 32 + kc) * 2;
      w0[r] = ep[0]; w1[r] = ep[1];
    }
  }
  float c = 0.f; // cell state lives in tid<32 registers
  for (int t = 0; t < 128; t++) {
    if (t == 0) {
      h_lds[tid] = 0.f;
    } else {
      uint64_t v; int it = 0;
      do {
        v = __hip_atomic_load(&hbuf[(size_t)t * 512 + tid],
                              __ATOMIC_RELAXED, __HIP_MEMORY_SCOPE_AGENT);
      } while ((uint32_t)(v >> 32) != (uint32_t)t && ++it < (1 << 22));
      h_lds[tid] = __uint_as_float((uint32_t)v);
    }
    __syncthreads();
    float hr[16];
#pragma unroll
    for (int q = 0; q < 16; q++) hr[q] = h_lds[kc + 32 * q]; // bank=kc, conflict-free
#pragma unroll
    for (int r = 0; r < 8; r++) {
      float s = 0.f;
      mac2(s, w0[r].x, hr[0], hr[1]);   mac2(s, w0[r].y, hr[2], hr[3]);
      mac2(s, w0[r].z, hr[4], hr[5]);   mac2(s, w0[r].w, hr[6], hr[7]);
      mac2(s, w1[r].x, hr[8], hr[9]);   mac2(s, w1[r].y, hr[10], hr[11]);
      mac2(s, w1[r].z, hr[12], hr[13]); mac2(s, w1[r].w, hr[14], hr[15]);
      s += __shfl_xor(s, 1);  s += __shfl_xor(s, 2);  s += __shfl_xor(s, 4);
      s += __shfl_xor(s, 8);  s += __shfl_xor(s, 16);
      if (kc == 0) gate_lds[rg * 8 + r] = s;
    }
    __syncthreads();
    if (tid < 32) {
      const float* xt = xgd + (size_t)t * cG + tid;
      float gi = gate_lds[tid]      + xt[0];
      float gf = gate_lds[32 + tid] + xt[512];
      float gg = gate_lds[64 + tid] + xt[1024];
      float go = gate_lds[96 + tid] + xt[1536];
      c = fast_sigmoid(gf) * c + fast_sigmoid(gi) * fast_tanh(gg);
      float h = fast_sigmoid(go) * fast_tanh(c);
      uint64_t pv = ((uint64_t)(uint32_t)(t + 1) << 32) | (uint64_t)__float_as_uint(h);
      __hip_atomic_store(&hbuf[(size_t)(t + 1) * 512 + bi * 32 + tid], pv,
                         __ATOMIC_RELAXED, __HIP_MEMORY_SCOPE_AGENT);
    }
  }
}

// ---------------- K3: u = h@UW^T + Ub ; s = softplus(h@SW^T + Sb) ----------------
__global__ __launch_bounds__(256) void k_us(const uint64_t* __restrict__ hf64,
                                            const uint64_t* __restrict__ hb64,
                                            const float* __restrict__ UW,
                                            const float* __restrict__ Ub,
                                            const float* __restrict__ SW,
                                            const float* __restrict__ Sb,
                                            float* __restrict__ u,
                                            float* __restrict__ s) {
  int tcb = blockIdx.x, rcb = blockIdx.y;
  __shared__ float hs[16][1024];
  int tid = threadIdx.x;
  const float2* hf2 = (const float2*)hf64;
  const float2* hb2 = (const float2*)hb64;
  for (int q = tid; q < 16 * 1024; q += 256) {
    int i = q >> 10, k = q & 1023;
    int T = tcb * 16 + i;
    float v = (k < 512) ? hf2[(size_t)(T + 1) * 512 + k].x
                        : hb2[(size_t)(128 - T) * 512 + (k - 512)].x;
    hs[i][k] = v;
  }
  __syncthreads();
  int rl = tid & 31, tp = tid >> 5;
  int rv = rcb * 32 + rl;
  const float* wrow = (rv < 512) ? (UW + (size_t)rv * 1024) : (SW + (size_t)(rv - 512) * 1024);
  float acc0 = 0.f, acc1 = 0.f;
  for (int k = 0; k < 1024; k += 4) {
    float4 w = *(const float4*)(wrow + k);
    float4 a = *(const float4*)(&hs[tp][k]);
    float4 b = *(const float4*)(&hs[tp + 8][k]);
    acc0 += w.x * a.x + w.y * a.y + w.z * a.z + w.w * a.w;
    acc1 += w.x * b.x + w.y * b.y + w.z * b.z + w.w * b.w;
  }
  int T0 = tcb * 16 + tp, T1 = T0 + 8;
  if (rv < 512) {
    float b = Ub[rv];
    u[(size_t)T0 * 512 + rv] = acc0 + b;
    u[(size_t)T1 * 512 + rv] = acc1 + b;
  } else {
    float b = Sb[rv - 512];
    float x0 = acc0 + b, x1 = acc1 + b;
    s[(size_t)T0 * 512 + rv - 512] = (x0 > 20.f) ? x0 : log1pf(__expf(x0));
    s[(size_t)T1 * 512 + rv - 512] = (x1 > 20.f) ? x1 : log1pf(__expf(x1));
  }
}

// ---------------- K3b: sample z1,z2 and accumulate KL ----------------
__global__ __launch_bounds__(256) void k_sample(const float* __restrict__ u,
                                                const float* __restrict__ s,
                                                float* __restrict__ z1,
                                                float* __restrict__ z2,
                                                float* __restrict__ acc_kl) {
  int idx = blockIdx.x * 256 + threadIdx.x;
  float uu = u[idx], ss = s[idx];
  z1[idx] = uu + ss * rng_normal((uint32_t)idx, 1u);
  z2[idx] = uu + ss * rng_normal((uint32_t)idx, 2u);
  float kle = 0.5f * (ss * ss + uu * uu - 1.0f - 2.0f * logf(fmaxf(ss, 1e-37f)));
  __shared__ float red[256];
  red[threadIdx.x] = kle;
  __syncthreads();
  for (int off = 128; off; off >>= 1) {
    if (threadIdx.x < off) red[threadIdx.x] += red[threadIdx.x + off];
    __syncthreads();
  }
  if (threadIdx.x == 0) atomicAdd(acc_kl, red[0]);
}

// ---------------- K4: fused logits GEMM + online (max,sumexp) + gathers ----------------
// 128 rows x 128 words tile, K in 16 chunks of 32. At[32][132] (A transposed, scalar
// broadcast reads), Bt[32][128] k-major with XOR swizzle col' = col ^ ((col>>5)&3)*4
// → all LDS ops <=2-way (free). Outer-product 8x8 microkernel.
__global__ __launch_bounds__(256) void k_logits(const float* __restrict__ z1,
                                                const float* __restrict__ z2,
                                                const float* __restrict__ fW,
                                                const float* __restrict__ fb,
                                                const float* __restrict__ gW,
                                                const float* __restrict__ gb,
                                                const int* __restrict__ words_l1,
                                                const int* __restrict__ words_l2,
                                                float* __restrict__ pm,
                                                float* __restrict__ g1,
                                                float* __restrict__ g2) {
  int gx = blockIdx.x, mat = blockIdx.y;
  const float* Z = mat ? z2 : z1;
  const float* W = mat ? gW : fW;
  const float* B = mat ? gb : fb;
  int w0 = gx * 128;
  __shared__ float At[32 * 132];
  __shared__ float Bt[32 * 128];
  __shared__ float2 red[128][16];
  __shared__ int wl1[128];
  __shared__ int wl2s[16];
  int tid = threadIdx.x;
  if (tid < 128) wl1[tid] = words_l1[tid];
  if (tid < 16) wl2s[tid] = words_l2[tid];
  int tx = tid & 15, ty = tid >> 4;
  int sr = tid >> 1, sh = tid & 1;                 // staging: row 0..127, k-half 0/1
  int scol = sr ^ (((sr >> 5) & 3) * 4);           // swizzled storage col for B row sr
  int swz = ((tx >> 2) & 3) * 4;
  int bc0 = (tx * 8) ^ swz;
  int bc1 = (tx * 8 + 4) ^ swz;
  float acc[8][8] = {};
  for (int kc = 0; kc < 16; kc++) {
    __syncthreads();
    {
      int kb = sh * 16;
      const float4* sa = (const float4*)(Z + (size_t)sr * 512 + kc * 32 + kb);
      const float4* sb = (const float4*)(W + (size_t)(w0 + sr) * 512 + kc * 32 + kb);
#pragma unroll
      for (int q = 0; q < 4; q++) {
        float4 a = sa[q];
        float4 b = sb[q];
        int k0 = kb + q * 4;
        At[(k0 + 0) * 132 + sr] = a.x;
        At[(k0 + 1) * 132 + sr] = a.y;
        At[(k0 + 2) * 132 + sr] = a.z;
        At[(k0 + 3) * 132 + sr] = a.w;
        Bt[(k0 + 0) * 128 + scol] = b.x;
        Bt[(k0 + 1) * 128 + scol] = b.y;
        Bt[(k0 + 2) * 128 + scol] = b.z;
        Bt[(k0 + 3) * 128 + scol] = b.w;
      }
    }
    __syncthreads();
#pragma unroll 4
    for (int k = 0; k < 32; k++) {
      float4 b0 = *(const float4*)(&Bt[k * 128 + bc0]);
      float4 b1 = *(const float4*)(&Bt[k * 128 + bc1]);
      float av[8];
#pragma unroll
      for (int i = 0; i < 8; i++) av[i] = At[k * 132 + ty * 8 + i];
#pragma unroll
      for (int i = 0; i < 8; i++) {
        acc[i][0] = fmaf(av[i], b0.x, acc[i][0]);
        acc[i][1] = fmaf(av[i], b0.y, acc[i][1]);
        acc[i][2] = fmaf(av[i], b0.z, acc[i][2]);
        acc[i][3] = fmaf(av[i], b0.w, acc[i][3]);
        acc[i][4] = fmaf(av[i], b1.x, acc[i][4]);
        acc[i][5] = fmaf(av[i], b1.y, acc[i][5]);
        acc[i][6] = fmaf(av[i], b1.z, acc[i][6]);
        acc[i][7] = fmaf(av[i], b1.w, acc[i][7]);
      }
    }
  }
  float bj[8];
#pragma unroll
  for (int j = 0; j < 8; j++) bj[j] = B[w0 + tx * 8 + j];
  // gathers (unique writer per target word)
  if (mat == 0) {
#pragma unroll
    for (int i = 0; i < 8; i++) {
      int row = ty * 8 + i;
      int d = wl1[row] - (w0 + tx * 8);
      if (d >= 0 && d < 8) {
        float v = 0.f;
#pragma unroll
        for (int j = 0; j < 8; j++) v = (j == d) ? (acc[i][j] + bj[j]) : v;
        g1[row] = v;
      }
    }
  } else {
    for (int l = 0; l < 16; l++) {
      int d = wl2s[l] - (w0 + tx * 8);
      if (d >= 0 && d < 8) {
#pragma unroll
        for (int i = 0; i < 8; i++) {
          float v = 0.f;
#pragma unroll
          for (int j = 0; j < 8; j++) v = (j == d) ? (acc[i][j] + bj[j]) : v;
          g2[(ty * 8 + i) * 16 + l] = v;
        }
      }
    }
  }
  // per-thread (max, sumexp) over its 8 words, per row
#pragma unroll
  for (int i = 0; i < 8; i++) {
    float m = -1e30f;
#pragma unroll
    for (int j = 0; j < 8; j++) m = fmaxf(m, acc[i][j] + bj[j]);
    float se = 0.f;
#pragma unroll
    for (int j = 0; j < 8; j++) se += __expf(acc[i][j] + bj[j] - m);
    red[ty * 8 + i][tx] = make_float2(m, se);
  }
  __syncthreads();
  if (tid < 128) {
    float m = -1e30f, se = 0.f;
    for (int x = 0; x < 16; x++) {
      float2 p = red[tid][x];
      if (p.x > m) { se = se * __expf(m - p.x) + p.y; m = p.x; }
      else se += p.y * __expf(p.x - m);
    }
    float2* dst = (float2*)pm + ((size_t)mat * 250 + gx) * 128 + tid;
    *dst = make_float2(m, se);
  }
}

// ---------------- K5: combine per-chunk (m,s) -> lse; accumulate terms ----------------
__global__ __launch_bounds__(256) void k_combine(const float* __restrict__ pm,
                                                 const float* __restrict__ g1,
                                                 const float* __restrict__ g2,
                                                 float* __restrict__ acc_terms) {
  int row = blockIdx.x, mat = blockIdx.y;
  int tid = threadIdx.x;
  const float2* p = (const float2*)pm + (size_t)mat * 250 * 128 + row;
  float m = -1e30f, se = 0.f;
  if (tid < 250) { float2 v = p[(size_t)tid * 128]; m = v.x; se = v.y; }
  __shared__ float2 red[256];
  red[tid] = make_float2(m, se);
  __syncthreads();
  for (int off = 128; off; off >>= 1) {
    if (tid < off) {
      float2 a = red[tid], b = red[tid + off];
      if (b.x > a.x) { a.y = a.y * __expf(a.x - b.x) + b.y; a.x = b.x; }
      else a.y += b.y * __expf(b.x - a.x);
      red[tid] = a;
    }
    __syncthreads();
  }
  if (tid == 0) {
    float lse = red[0].x + logf(red[0].y);
    float v;
    if (mat == 0) v = g1[row] - lse;
    else {
      float sg = 0.f;
      for (int l = 0; l < 16; l++) sg += g2[row * 16 + l];
      v = sg * (1.0f / 16.0f) - lse;
    }
    atomicAdd(acc_terms, v);
  }
}

// ---------------- K6: final scalar ----------------
__global__ void k_final(const float* __restrict__ acc, float* __restrict__ out) {
  out[0] = acc[1] - acc[0]; // -kl + term1 + term2
}

extern "C" void kernel_launch(void* const* d_in, const int* in_sizes, int n_in,
                              void* d_out, int out_size, void* d_ws, size_t ws_size,
                              hipStream_t stream) {
  (void)in_sizes; (void)n_in; (void)out_size; (void)ws_size;
  const int*   words_l1 = (const int*)d_in[0];
  const int*   words_l2 = (const int*)d_in[1];
  const float* emb      = (const float*)d_in[2];
  const float* Wih_f    = (const float*)d_in[3];
  const float* Whh_f    = (const float*)d_in[4];
  const float* bih_f    = (const float*)d_in[5];
  const float* bhh_f    = (const float*)d_in[6];
  const float* Wih_b    = (const float*)d_in[7];
  const float* Whh_b    = (const float*)d_in[8];
  const float* bih_b    = (const float*)d_in[9];
  const float* bhh_b    = (const float*)d_in[10];
  const float* UW       = (const float*)d_in[11];
  const float* Ub       = (const float*)d_in[12];
  const float* SW       = (const float*)d_in[13];
  const float* Sb       = (const float*)d_in[14];
  const float* fW       = (const float*)d_in[15];
  const float* fb       = (const float*)d_in[16];
  const float* gW       = (const float*)d_in[17];
  const float* gb       = (const float*)d_in[18];

  char* ws = (char*)d_ws;
  float*    dum  = (float*)(ws + O_DUM);
  float*    acc  = (float*)(ws + O_ACC);
  uint16_t* wpk  = (uint16_t*)(ws + O_WPK);
  float*    xg   = (float*)(ws + O_XG);
  uint64_t* hf   = (uint64_t*)(ws + O_HF);
  uint64_t* hb   = (uint64_t*)(ws + O_HB);
  float*    u    = (float*)(ws + O_U);
  float*    s    = (float*)(ws + O_S);
  float*    z1   = (float*)(ws + O_Z1);
  float*    z2   = (float*)(ws + O_Z2);
  float*    pm   = (float*)(ws + O_PM);
  float*    g1   = (float*)(ws + O_G1);
  float*    g2   = (float*)(ws + O_G2);

  hipMemsetAsync(ws, 0, 2048, stream); // accumulators

  k_pack<<<512, 256, 0, stream>>>(Whh_f, Whh_b, wpk);
  k_embxg<<<dim3(8, 16, 2), 256, 0, stream>>>(words_l1, emb, Wih_f, bih_f, bhh_f,
                                              Wih_b, bih_b, bhh_b, xg);
  k_lstm<<<256, 512, 0, stream>>>(wpk, xg, hf, hb, fW, gW, dum);
  k_us<<<dim3(8, 32), 256, 0, stream>>>(hf, hb, UW, Ub, SW, Sb, u, s);
  k_sample<<<256, 256, 0, stream>>>(u, s, z1, z2, &acc[0]);
  k_logits<<<dim3(250, 2), 256, 0, stream>>>(z1, z2, fW, fb, gW, gb,
                                             words_l1, words_l2, pm, g1, g2);
  k_combine<<<dim3(128, 2), 256, 0, stream>>>(pm, g1, g2, &acc[1]);
  k_final<<<1, 1, 0, stream>>>(acc, (float*)d_out);
}

// Round 3
// 734.615 us; speedup vs baseline: 1.1559x; 1.0016x over previous
//
#include <hip/hip_runtime.h>
#include <stdint.h>

// Problem dims
static constexpr int cN1 = 128;   // src tokens
static constexpr int cE  = 256;   // embedding
static constexpr int cH  = 512;   // hidden
static constexpr int cV  = 32000; // vocab
static constexpr int cG  = 4 * cH; // 2048 gate rows

// ---------------- ws layout (bytes) ----------------
static constexpr size_t O_DUM = 0;                             // dummy sink (never written)
static constexpr size_t O_ACC = 1024;                          // float[2]: kl, terms
static constexpr size_t O_WPK = 4096;                          // bf16 [2][2048][512] packed
static constexpr size_t O_XG  = O_WPK + 2ull * cG * cH * 2;    // f32 [2][128][2048]
static constexpr size_t O_HF  = O_XG  + 2ull * cN1 * cG * 4;   // (val f32 lo, tag u32 hi) [129][512]
static constexpr size_t O_HB  = O_HF  + 129ull * cH * 8;
static constexpr size_t O_U   = O_HB  + 129ull * cH * 8;       // f32 [128][512]
static constexpr size_t O_S   = O_U   + (size_t)cN1 * cH * 4;
static constexpr size_t O_Z1  = O_S   + (size_t)cN1 * cH * 4;
static constexpr size_t O_Z2  = O_Z1  + (size_t)cN1 * cH * 4;
static constexpr size_t O_PM  = O_Z2  + (size_t)cN1 * cH * 4;  // float2 [2][250][128]
static constexpr size_t O_G1  = O_PM  + 2ull * 250 * 128 * 8;  // f32 [128]
static constexpr size_t O_G2  = O_G1  + 512;                   // f32 [128][16]

// ---------------- helpers ----------------
__device__ inline uint32_t f2bf(float f) {
  uint32_t x = __float_as_uint(f);
  return (x + 0x7FFFu + ((x >> 16) & 1u)) >> 16; // RNE bf16
}
__device__ inline void mac2(float& s, uint32_t w, float h0, float h1) {
  s += __uint_as_float(w << 16) * h0;
  s += __uint_as_float(w & 0xffff0000u) * h1;
}
__device__ inline uint64_t splitmix64(uint64_t x) {
  x += 0x9E3779B97F4A7C15ull;
  x = (x ^ (x >> 30)) * 0xBF58476D1CE4E5B9ull;
  x = (x ^ (x >> 27)) * 0x94D049BB133111EBull;
  return x ^ (x >> 31);
}
__device__ inline float rng_normal(uint32_t idx, uint32_t stream_id) {
  uint64_t h = splitmix64(((uint64_t)stream_id << 32) | (uint64_t)idx);
  uint32_t a = (uint32_t)(h >> 32), b = (uint32_t)h;
  float u1 = (float)((a >> 8) + 1u) * (1.0f / 16777217.0f); // (0,1]
  float u2 = (float)(b >> 8) * (1.0f / 16777216.0f);
  float r = sqrtf(-2.0f * logf(u1));
  return r * __cosf(6.28318530717958647692f * u2);
}
__device__ inline float fast_sigmoid(float x) { return 1.f / (1.f + __expf(-x)); }
__device__ inline float fast_tanh(float x) {
  float e = __expf(2.f * x);
  return (e - 1.f) / (e + 1.f);
}

// ---------------- K0: pack Whh (both dirs) into per-block bf16 layout ----------------
// wpk per (dir,bi): 128 local rows x 32 kc x 16 bf16. Entry (lr,kc), uint32 m (0..7):
//   lo = W[G][kc+64m], hi = W[G][kc+64m+32];  G = (lr>>5)*512 + bi*32 + (lr&31)
__global__ __launch_bounds__(256) void k_pack(const float* __restrict__ Whh_f,
                                              const float* __restrict__ Whh_b,
                                              uint16_t* __restrict__ wpk) {
  int d = blockIdx.x * 256 + threadIdx.x; // 131072 threads: one per (dir,bi,rg,r,kc)
  int kc  = d & 31;
  int r   = (d >> 5) & 7;
  int rg  = (d >> 8) & 15;
  int bi  = (d >> 12) & 15;
  int dir = (d >> 16) & 1;
  int lr = rg * 8 + r;
  int G  = (lr >> 5) * cH + bi * 32 + (lr & 31);
  const float* src = (dir ? Whh_b : Whh_f) + (size_t)G * cH;
  uint32_t m[8];
#pragma unroll
  for (int q = 0; q < 8; q++) {
    float lo = src[kc + 64 * q];
    float hi = src[kc + 64 * q + 32];
    m[q] = f2bf(lo) | (f2bf(hi) << 16);
  }
  uint4* dst = (uint4*)wpk + ((size_t)(dir * 16 + bi) * 8192 + ((size_t)lr * 32 + kc) * 2);
  dst[0] = make_uint4(m[0], m[1], m[2], m[3]);
  dst[1] = make_uint4(m[4], m[5], m[6], m[7]);
}

// ---------------- K1: embedding gather + xg = x@Wih^T + bih + bhh (both dirs) ----------------
__global__ __launch_bounds__(256) void k_embxg(const int* __restrict__ words,
                                               const float* __restrict__ emb,
                                               const float* __restrict__ Wih_f,
                                               const float* __restrict__ bih_f,
                                               const float* __restrict__ bhh_f,
                                               const float* __restrict__ Wih_b,
                                               const float* __restrict__ bih_b,
                                               const float* __restrict__ bhh_b,
                                               float* __restrict__ xg) {
  int tc = blockIdx.x, rc = blockIdx.y, dir = blockIdx.z;
  const float* Wih = dir ? Wih_b : Wih_f;
  const float* bi_ = dir ? bih_b : bih_f;
  const float* bh_ = dir ? bhh_b : bhh_f;
  __shared__ float xs[16][cE];
  __shared__ float bs[128][20];
  int tid = threadIdx.x;
  {
    int i = tid >> 4, part = tid & 15;
    int tg = tc * 16 + i;
    int tok = dir ? (127 - tg) : tg;
    int w = words[tok];
    const float4* src = (const float4*)(emb + (size_t)w * cE + part * 16);
    float4* dst = (float4*)(&xs[i][part * 16]);
    dst[0] = src[0]; dst[1] = src[1]; dst[2] = src[2]; dst[3] = src[3];
  }
  float acc[2][4] = {};
  int tx = tid & 31;
  int ty = tid >> 5;
  for (int kc = 0; kc < 16; kc++) {
    __syncthreads();
    {
      int r = tid >> 1, half = tid & 1;
      const float4* src = (const float4*)(Wih + (size_t)(rc * 128 + r) * cE + kc * 16 + half * 8);
      float4* dst = (float4*)(&bs[r][half * 8]);
      dst[0] = src[0]; dst[1] = src[1];
    }
    __syncthreads();
#pragma unroll
    for (int k4 = 0; k4 < 4; k4++) {
      float4 a0 = *(const float4*)(&xs[ty * 2 + 0][kc * 16 + k4 * 4]);
      float4 a1 = *(const float4*)(&xs[ty * 2 + 1][kc * 16 + k4 * 4]);
#pragma unroll
      for (int j = 0; j < 4; j++) {
        float4 b = *(const float4*)(&bs[tx * 4 + j][k4 * 4]);
        acc[0][j] += a0.x * b.x + a0.y * b.y + a0.z * b.z + a0.w * b.w;
        acc[1][j] += a1.x * b.x + a1.y * b.y + a1.z * b.z + a1.w * b.w;
      }
    }
  }
#pragma unroll
  for (int i = 0; i < 2; i++) {
    int tg = tc * 16 + ty * 2 + i;
#pragma unroll
    for (int j = 0; j < 4; j++) {
      int r = rc * 128 + tx * 4 + j;
      xg[((size_t)dir * cN1 + tg) * cG + r] = acc[i][j] + bi_[r] + bh_[r];
    }
  }
}

// ---------------- K2: LSTM scan — register weights, throttled tagged-data sync ----------------
// 256 blocks x 512 thr; active blocks: blockIdx%8 = dir(0/1), blockIdx/8 < 16 = bi.
// All 256 blocks are co-resident (1/CU): correctness never depends on XCD placement.
// Sync: h element = uint64 {tag=step (hi32), f32 bits (lo32)} stored with one relaxed
// agent atomic. Only wave 1 (tid 64..127) polls, 8 concurrent loads per sweep per thread
// -> 2K pollers device-wide (was 16K in R2, which flooded the coherence fabric).
__global__ __launch_bounds__(512, 1) void k_lstm(const uint16_t* __restrict__ wpk,
                                                 const float* __restrict__ xg,
                                                 uint64_t* __restrict__ hf64,
                                                 uint64_t* __restrict__ hb64,
                                                 const float* __restrict__ fW,
                                                 const float* __restrict__ gW,
                                                 float* __restrict__ dummy) {
  int xcd = blockIdx.x & 7;
  int wk  = blockIdx.x >> 3;
  int tid = threadIdx.x;
  if (xcd >= 2 || wk >= 16) {
    // idle blocks: warm fW/gW into LLC for k_logits
    const size_t half4 = (size_t)cV * cH / 4; // float4 count per matrix
    float s = 0.f;
    for (size_t i = (size_t)blockIdx.x * 512 + tid; i < 2 * half4; i += 256ull * 512) {
      float4 v = (i < half4) ? ((const float4*)fW)[i] : ((const float4*)gW)[i - half4];
      s += v.x + v.y + v.z + v.w;
    }
    if (s == 123456789.0f) dummy[0] = s; // never true; defeats DCE
    return;
  }
  int dir = xcd, bi = wk;
  const float* xgd = xg + (size_t)dir * cN1 * cG;
  uint64_t* hbuf = dir ? hb64 : hf64;
  int kc = tid & 31, rg = tid >> 5;
  __shared__ float h_lds[512];
  __shared__ float xg_lds[128];
  __shared__ float gate_lds[128];
  // weights -> registers (64 VGPRs of bf16 pairs)
  uint4 w0[8], w1[8];
  {
    const uint4* wb = (const uint4*)wpk + (size_t)(dir * 16 + bi) * 8192;
#pragma unroll
    for (int r = 0; r < 8; r++) {
      const uint4* ep = wb + ((size_t)(rg * 8 + r) * 32 + kc) * 2;
      w0[r] = ep[0]; w1[r] = ep[1];
    }
  }
  float c = 0.f; // cell state lives in tid<32 registers
  h_lds[tid < 512 ? tid : 0] = 0.f; // h_0 = 0
  __syncthreads();
  for (int t = 0; t < 128; t++) {
    // prefetch this block's 128 xg gate biases for step t (independent of h)
    if (tid >= 256 && tid < 384) {
      int j = tid - 256; // gate row G = (j>>5)*512 + bi*32 + (j&31)
      xg_lds[j] = xgd[(size_t)t * cG + ((j >> 5) << 9) + bi * 32 + (j & 31)];
    }
    float hr[16];
#pragma unroll
    for (int q = 0; q < 16; q++) hr[q] = h_lds[kc + 32 * q]; // bank=kc, conflict-free
#pragma unroll
    for (int r = 0; r < 8; r++) {
      float s = 0.f;
      mac2(s, w0[r].x, hr[0], hr[1]);   mac2(s, w0[r].y, hr[2], hr[3]);
      mac2(s, w0[r].z, hr[4], hr[5]);   mac2(s, w0[r].w, hr[6], hr[7]);
      mac2(s, w1[r].x, hr[8], hr[9]);   mac2(s, w1[r].y, hr[10], hr[11]);
      mac2(s, w1[r].z, hr[12], hr[13]); mac2(s, w1[r].w, hr[14], hr[15]);
      s += __shfl_xor(s, 1);  s += __shfl_xor(s, 2);  s += __shfl_xor(s, 4);
      s += __shfl_xor(s, 8);  s += __shfl_xor(s, 16);
      if (kc == 0) gate_lds[rg * 8 + r] = s;
    }
    __syncthreads(); // gate_lds + xg_lds ready; all h_lds reads done
    if (tid < 64) {
      if (tid < 32) { // producer half-wave: activation + tagged store
        float gi = gate_lds[tid]      + xg_lds[tid];
        float gf = gate_lds[32 + tid] + xg_lds[32 + tid];
        float gg = gate_lds[64 + tid] + xg_lds[64 + tid];
        float go = gate_lds[96 + tid] + xg_lds[96 + tid];
        c = fast_sigmoid(gf) * c + fast_sigmoid(gi) * fast_tanh(gg);
        float h = fast_sigmoid(go) * fast_tanh(c);
        uint64_t pv = ((uint64_t)(uint32_t)(t + 1) << 32) | (uint64_t)__float_as_uint(h);
        __hip_atomic_store(&hbuf[(size_t)(t + 1) * 512 + bi * 32 + tid], pv,
                           __ATOMIC_RELAXED, __HIP_MEMORY_SCOPE_AGENT);
      }
    } else if (tid < 128 && t < 127) {
      // poller wave: gather h_{t+1} (overlaps producers' activation in wave 0)
      int p = tid - 64;
      const uint64_t* ep = &hbuf[(size_t)(t + 1) * 512 + p * 8];
      uint64_t v[8];
      uint32_t want = (uint32_t)(t + 1);
      bool done = false;
      int it = 0;
      while (!done && it < (1 << 13)) {
        done = true;
#pragma unroll
        for (int j = 0; j < 8; j++)
          v[j] = __hip_atomic_load(&ep[j], __ATOMIC_RELAXED, __HIP_MEMORY_SCOPE_AGENT);
#pragma unroll
        for (int j = 0; j < 8; j++) done = done && ((uint32_t)(v[j] >> 32) == want);
        it++;
      }
#pragma unroll
      for (int j = 0; j < 8; j++) h_lds[p * 8 + j] = __uint_as_float((uint32_t)v[j]);
    }
    __syncthreads(); // h_lds now holds h_{t+1}
  }
}

// ---------------- K3: u = h@UW^T + Ub ; s = softplus(h@SW^T + Sb) ----------------
__global__ __launch_bounds__(256) void k_us(const uint64_t* __restrict__ hf64,
                                            const uint64_t* __restrict__ hb64,
                                            const float* __restrict__ UW,
                                            const float* __restrict__ Ub,
                                            const float* __restrict__ SW,
                                            const float* __restrict__ Sb,
                                            float* __restrict__ u,
                                            float* __restrict__ s) {
  int tcb = blockIdx.x, rcb = blockIdx.y;
  __shared__ float hs[16][1024];
  int tid = threadIdx.x;
  const float2* hf2 = (const float2*)hf64;
  const float2* hb2 = (const float2*)hb64;
  for (int q = tid; q < 16 * 1024; q += 256) {
    int i = q >> 10, k = q & 1023;
    int T = tcb * 16 + i;
    float v = (k < 512) ? hf2[(size_t)(T + 1) * 512 + k].x
                        : hb2[(size_t)(128 - T) * 512 + (k - 512)].x;
    hs[i][k] = v;
  }
  __syncthreads();
  int rl = tid & 31, tp = tid >> 5;
  int rv = rcb * 32 + rl;
  const float* wrow = (rv < 512) ? (UW + (size_t)rv * 1024) : (SW + (size_t)(rv - 512) * 1024);
  float acc0 = 0.f, acc1 = 0.f;
  for (int k = 0; k < 1024; k += 4) {
    float4 w = *(const float4*)(wrow + k);
    float4 a = *(const float4*)(&hs[tp][k]);
    float4 b = *(const float4*)(&hs[tp + 8][k]);
    acc0 += w.x * a.x + w.y * a.y + w.z * a.z + w.w * a.w;
    acc1 += w.x * b.x + w.y * b.y + w.z * b.z + w.w * b.w;
  }
  int T0 = tcb * 16 + tp, T1 = T0 + 8;
  if (rv < 512) {
    float b = Ub[rv];
    u[(size_t)T0 * 512 + rv] = acc0 + b;
    u[(size_t)T1 * 512 + rv] = acc1 + b;
  } else {
    float b = Sb[rv - 512];
    float x0 = acc0 + b, x1 = acc1 + b;
    s[(size_t)T0 * 512 + rv - 512] = (x0 > 20.f) ? x0 : log1pf(__expf(x0));
    s[(size_t)T1 * 512 + rv - 512] = (x1 > 20.f) ? x1 : log1pf(__expf(x1));
  }
}

// ---------------- K3b: sample z1,z2 and accumulate KL ----------------
__global__ __launch_bounds__(256) void k_sample(const float* __restrict__ u,
                                                const float* __restrict__ s,
                                                float* __restrict__ z1,
                                                float* __restrict__ z2,
                                                float* __restrict__ acc_kl) {
  int idx = blockIdx.x * 256 + threadIdx.x;
  float uu = u[idx], ss = s[idx];
  z1[idx] = uu + ss * rng_normal((uint32_t)idx, 1u);
  z2[idx] = uu + ss * rng_normal((uint32_t)idx, 2u);
  float kle = 0.5f * (ss * ss + uu * uu - 1.0f - 2.0f * logf(fmaxf(ss, 1e-37f)));
  __shared__ float red[256];
  red[threadIdx.x] = kle;
  __syncthreads();
  for (int off = 128; off; off >>= 1) {
    if (threadIdx.x < off) red[threadIdx.x] += red[threadIdx.x + off];
    __syncthreads();
  }
  if (threadIdx.x == 0) atomicAdd(acc_kl, red[0]);
}

// ---------------- K4: fused logits GEMM + online (max,sumexp) + gathers ----------------
__global__ __launch_bounds__(256) void k_logits(const float* __restrict__ z1,
                                                const float* __restrict__ z2,
                                                const float* __restrict__ fW,
                                                const float* __restrict__ fb,
                                                const float* __restrict__ gW,
                                                const float* __restrict__ gb,
                                                const int* __restrict__ words_l1,
                                                const int* __restrict__ words_l2,
                                                float* __restrict__ pm,
                                                float* __restrict__ g1,
                                                float* __restrict__ g2) {
  int gx = blockIdx.x, mat = blockIdx.y;
  const float* Z = mat ? z2 : z1;
  const float* W = mat ? gW : fW;
  const float* B = mat ? gb : fb;
  int w0 = gx * 128;
  __shared__ float At[32 * 132];
  __shared__ float Bt[32 * 128];
  __shared__ float2 red[128][16];
  __shared__ int wl1[128];
  __shared__ int wl2s[16];
  int tid = threadIdx.x;
  if (tid < 128) wl1[tid] = words_l1[tid];
  if (tid < 16) wl2s[tid] = words_l2[tid];
  int tx = tid & 15, ty = tid >> 4;
  int sr = tid >> 1, sh = tid & 1;
  int scol = sr ^ (((sr >> 5) & 3) * 4);
  int swz = ((tx >> 2) & 3) * 4;
  int bc0 = (tx * 8) ^ swz;
  int bc1 = (tx * 8 + 4) ^ swz;
  float acc[8][8] = {};
  for (int kc = 0; kc < 16; kc++) {
    __syncthreads();
    {
      int kb = sh * 16;
      const float4* sa = (const float4*)(Z + (size_t)sr * 512 + kc * 32 + kb);
      const float4* sb = (const float4*)(W + (size_t)(w0 + sr) * 512 + kc * 32 + kb);
#pragma unroll
      for (int q = 0; q < 4; q++) {
        float4 a = sa[q];
        float4 b = sb[q];
        int k0 = kb + q * 4;
        At[(k0 + 0) * 132 + sr] = a.x;
        At[(k0 + 1) * 132 + sr] = a.y;
        At[(k0 + 2) * 132 + sr] = a.z;
        At[(k0 + 3) * 132 + sr] = a.w;
        Bt[(k0 + 0) * 128 + scol] = b.x;
        Bt[(k0 + 1) * 128 + scol] = b.y;
        Bt[(k0 + 2) * 128 + scol] = b.z;
        Bt[(k0 + 3) * 128 + scol] = b.w;
      }
    }
    __syncthreads();
#pragma unroll 4
    for (int k = 0; k < 32; k++) {
      float4 b0 = *(const float4*)(&Bt[k * 128 + bc0]);
      float4 b1 = *(const float4*)(&Bt[k * 128 + bc1]);
      float av[8];
#pragma unroll
      for (int i = 0; i < 8; i++) av[i] = At[k * 132 + ty * 8 + i];
#pragma unroll
      for (int i = 0; i < 8; i++) {
        acc[i][0] = fmaf(av[i], b0.x, acc[i][0]);
        acc[i][1] = fmaf(av[i], b0.y, acc[i][1]);
        acc[i][2] = fmaf(av[i], b0.z, acc[i][2]);
        acc[i][3] = fmaf(av[i], b0.w, acc[i][3]);
        acc[i][4] = fmaf(av[i], b1.x, acc[i][4]);
        acc[i][5] = fmaf(av[i], b1.y, acc[i][5]);
        acc[i][6] = fmaf(av[i], b1.z, acc[i][6]);
        acc[i][7] = fmaf(av[i], b1.w, acc[i][7]);
      }
    }
  }
  float bj[8];
#pragma unroll
  for (int j = 0; j < 8; j++) bj[j] = B[w0 + tx * 8 + j];
  if (mat == 0) {
#pragma unroll
    for (int i = 0; i < 8; i++) {
      int row = ty * 8 + i;
      int d = wl1[row] - (w0 + tx * 8);
      if (d >= 0 && d < 8) {
        float v = 0.f;
#pragma unroll
        for (int j = 0; j < 8; j++) v = (j == d) ? (acc[i][j] + bj[j]) : v;
        g1[row] = v;
      }
    }
  } else {
    for (int l = 0; l < 16; l++) {
      int d = wl2s[l] - (w0 + tx * 8);
      if (d >= 0 && d < 8) {
#pragma unroll
        for (int i = 0; i < 8; i++) {
          float v = 0.f;
#pragma unroll
          for (int j = 0; j < 8; j++) v = (j == d) ? (acc[i][j] + bj[j]) : v;
          g2[(ty * 8 + i) * 16 + l] = v;
        }
      }
    }
  }
#pragma unroll
  for (int i = 0; i < 8; i++) {
    float m = -1e30f;
#pragma unroll
    for (int j = 0; j < 8; j++) m = fmaxf(m, acc[i][j] + bj[j]);
    float se = 0.f;
#pragma unroll
    for (int j = 0; j < 8; j++) se += __expf(acc[i][j] + bj[j] - m);
    red[ty * 8 + i][tx] = make_float2(m, se);
  }
  __syncthreads();
  if (tid < 128) {
    float m = -1e30f, se = 0.f;
    for (int x = 0; x < 16; x++) {
      float2 p = red[tid][x];
      if (p.x > m) { se = se * __expf(m - p.x) + p.y; m = p.x; }
      else se += p.y * __expf(p.x - m);
    }
    float2* dst = (float2*)pm + ((size_t)mat * 250 + gx) * 128 + tid;
    *dst = make_float2(m, se);
  }
}

// ---------------- K5: combine per-chunk (m,s) -> lse; accumulate terms ----------------
__global__ __launch_bounds__(256) void k_combine(const float* __restrict__ pm,
                                                 const float* __restrict__ g1,
                                                 const float* __restrict__ g2,
                                                 float* __restrict__ acc_terms) {
  int row = blockIdx.x, mat = blockIdx.y;
  int tid = threadIdx.x;
  const float2* p = (const float2*)pm + (size_t)mat * 250 * 128 + row;
  float m = -1e30f, se = 0.f;
  if (tid < 250) { float2 v = p[(size_t)tid * 128]; m = v.x; se = v.y; }
  __shared__ float2 red[256];
  red[tid] = make_float2(m, se);
  __syncthreads();
  for (int off = 128; off; off >>= 1) {
    if (tid < off) {
      float2 a = red[tid], b = red[tid + off];
      if (b.x > a.x) { a.y = a.y * __expf(a.x - b.x) + b.y; a.x = b.x; }
      else a.y += b.y * __expf(b.x - a.x);
      red[tid] = a;
    }
    __syncthreads();
  }
  if (tid == 0) {
    float lse = red[0].x + logf(red[0].y);
    float v;
    if (mat == 0) v = g1[row] - lse;
    else {
      float sg = 0.f;
      for (int l = 0; l < 16; l++) sg += g2[row * 16 + l];
      v = sg * (1.0f / 16.0f) - lse;
    }
    atomicAdd(acc_terms, v);
  }
}

// ---------------- K6: final scalar ----------------
__global__ void k_final(const float* __restrict__ acc, float* __restrict__ out) {
  out[0] = acc[1] - acc[0]; // -kl + term1 + term2
}

extern "C" void kernel_launch(void* const* d_in, const int* in_sizes, int n_in,
                              void* d_out, int out_size, void* d_ws, size_t ws_size,
                              hipStream_t stream) {
  (void)in_sizes; (void)n_in; (void)out_size; (void)ws_size;
  const int*   words_l1 = (const int*)d_in[0];
  const int*   words_l2 = (const int*)d_in[1];
  const float* emb      = (const float*)d_in[2];
  const float* Wih_f    = (const float*)d_in[3];
  const float* Whh_f    = (const float*)d_in[4];
  const float* bih_f    = (const float*)d_in[5];
  const float* bhh_f    = (const float*)d_in[6];
  const float* Wih_b    = (const float*)d_in[7];
  const float* Whh_b    = (const float*)d_in[8];
  const float* bih_b    = (const float*)d_in[9];
  const float* bhh_b    = (const float*)d_in[10];
  const float* UW       = (const float*)d_in[11];
  const float* Ub       = (const float*)d_in[12];
  const float* SW       = (const float*)d_in[13];
  const float* Sb       = (const float*)d_in[14];
  const float* fW       = (const float*)d_in[15];
  const float* fb       = (const float*)d_in[16];
  const float* gW       = (const float*)d_in[17];
  const float* gb       = (const float*)d_in[18];

  char* ws = (char*)d_ws;
  float*    dum  = (float*)(ws + O_DUM);
  float*    acc  = (float*)(ws + O_ACC);
  uint16_t* wpk  = (uint16_t*)(ws + O_WPK);
  float*    xg   = (float*)(ws + O_XG);
  uint64_t* hf   = (uint64_t*)(ws + O_HF);
  uint64_t* hb   = (uint64_t*)(ws + O_HB);
  float*    u    = (float*)(ws + O_U);
  float*    s    = (float*)(ws + O_S);
  float*    z1   = (float*)(ws + O_Z1);
  float*    z2   = (float*)(ws + O_Z2);
  float*    pm   = (float*)(ws + O_PM);
  float*    g1   = (float*)(ws + O_G1);
  float*    g2   = (float*)(ws + O_G2);

  hipMemsetAsync(ws, 0, 2048, stream); // accumulators

  k_pack<<<512, 256, 0, stream>>>(Whh_f, Whh_b, wpk);
  k_embxg<<<dim3(8, 16, 2), 256, 0, stream>>>(words_l1, emb, Wih_f, bih_f, bhh_f,
                                              Wih_b, bih_b, bhh_b, xg);
  k_lstm<<<256, 512, 0, stream>>>(wpk, xg, hf, hb, fW, gW, dum);
  k_us<<<dim3(8, 32), 256, 0, stream>>>(hf, hb, UW, Ub, SW, Sb, u, s);
  k_sample<<<256, 256, 0, stream>>>(u, s, z1, z2, &acc[0]);
  k_logits<<<dim3(250, 2), 256, 0, stream>>>(z1, z2, fW, fb, gW, gb,
                                             words_l1, words_l2, pm, g1, g2);
  k_combine<<<dim3(128, 2), 256, 0, stream>>>(pm, g1, g2, &acc[1]);
  k_final<<<1, 1, 0, stream>>>(acc, (float*)d_out);
}